// Round 11
// baseline (1014.106 us; speedup 1.0000x reference)
//
#include <hip/hip_runtime.h>
#include <math.h>

// B=64, T=496, C=128, DM=512, NH=8, FF=2048, NS=3, NL=2
// Verified: soft-DTW => z2==0 => h = pos_enc => scalar output broadcast.
// Layer 2 computes only row 495 (K,V full). R11: mega-kernel with SOFTWARE
// grid barrier (device-scope atomics + fences) launched as a normal kernel —
// R10's hipLaunchCooperativeKernel returned an error (clean sync, zero
// output => API failure, not kernel). 114KB LDS => 1 block/CU => all 256
// blocks co-resident => software barrier is safe. Stage bodies verbatim R9.

#define T_SEQ 496
#define DM    512
#define NH    8
#define HD    64
#define FF    2048
#define SEQF  (T_SEQ * DM)
#define NBLK  256

typedef unsigned short ushort_t;
typedef short bf16x8 __attribute__((ext_vector_type(8)));
typedef ushort_t u16x8 __attribute__((ext_vector_type(8)));
typedef float f32x4 __attribute__((ext_vector_type(4)));

struct MegaP {
    const float *Wq0, *Wk0, *Wv0, *Wo0, *W10, *W20, *Wk1, *Wv1;   // conv sources
    const float *Wq1, *Wo1, *W11, *W21;                           // L2 fp32 weights
    const float *ln1_g, *ln1_b, *ln2_g, *ln2_b, *fn_g, *fn_b, *Wc, *bc;
    const float *ebq, *ebk, *ebv, *ebo, *eb1, *eb2;
    float *H, *XN, *Qb, *Kb, *Vb, *Pp, *O2, *xrow, *Fr;
    ushort_t *XNh, *XNl, *Obh, *Obl, *Fbh, *Fbl, *WTh, *WTl;
    unsigned *bar;                                                // [cnt, gen]
    float *out;
};

// ------------------------- software grid barrier ----------------------------
__device__ void gsync(unsigned* bar) {
    __syncthreads();
    if (threadIdx.x == 0) {
        __threadfence();   // release: write back this XCD's L2
        unsigned gen = __hip_atomic_load(&bar[1], __ATOMIC_RELAXED, __HIP_MEMORY_SCOPE_AGENT);
        unsigned arrived = __hip_atomic_fetch_add(&bar[0], 1u, __ATOMIC_ACQ_REL, __HIP_MEMORY_SCOPE_AGENT);
        if (arrived == NBLK - 1) {
            __hip_atomic_store(&bar[0], 0u, __ATOMIC_RELAXED, __HIP_MEMORY_SCOPE_AGENT);
            __hip_atomic_fetch_add(&bar[1], 1u, __ATOMIC_RELEASE, __HIP_MEMORY_SCOPE_AGENT);
        } else {
            long spin = 0;
            while (__hip_atomic_load(&bar[1], __ATOMIC_ACQUIRE, __HIP_MEMORY_SCOPE_AGENT) == gen) {
                if (++spin > (1L << 20)) break;   // failsafe: no infinite hang
            }
        }
        __threadfence();   // acquire: invalidate stale lines
    }
    __syncthreads();
}

__device__ __forceinline__ void split_bf16(float x, ushort_t& h, ushort_t& l) {
    unsigned u = __float_as_uint(x);
    h = (ushort_t)(u >> 16);
    float fh = __uint_as_float(u & 0xFFFF0000u);
    l = (ushort_t)(__float_as_uint(x - fh) >> 16);
}

__device__ __forceinline__ float pe_val(int pos, int c) {
    int i = c >> 1;
    float div = expf((float)(2 * i) * (-9.210340371976184f / 512.0f));
    float ang = (float)pos * div;
    return (c & 1) ? cosf(ang) : sinf(ang);
}

// --------------------------- pos-enc + LN row -------------------------------
__device__ void ln_pe_row(int pos, const MegaP& p, float* red) {
    int t = threadIdx.x;
    size_t base = (size_t)pos * DM;
    __syncthreads();
    float v0 = pe_val(pos, t), v1 = pe_val(pos, t + 256);
    p.H[base + t] = v0; p.H[base + t + 256] = v1;
    red[t] = v0 + v1;
    __syncthreads();
    for (int o = 128; o > 0; o >>= 1) { if (t < o) red[t] += red[t + o]; __syncthreads(); }
    float mu = red[0] * (1.0f / 512.0f);
    __syncthreads();
    float d0 = v0 - mu, d1 = v1 - mu;
    red[t] = d0 * d0 + d1 * d1;
    __syncthreads();
    for (int o = 128; o > 0; o >>= 1) { if (t < o) red[t] += red[t + o]; __syncthreads(); }
    float inv = rsqrtf(red[0] * (1.0f / 512.0f) + 1e-5f);
    float y0 = d0 * inv * p.ln1_g[t] + p.ln1_b[t];
    float y1 = d1 * inv * p.ln1_g[t + 256] + p.ln1_b[t + 256];
    p.XN[base + t] = y0; p.XN[base + t + 256] = y1;
    ushort_t h, l;
    split_bf16(y0, h, l); p.XNh[base + t] = h;       p.XNl[base + t] = l;
    split_bf16(y1, h, l); p.XNh[base + t + 256] = h; p.XNl[base + t + 256] = l;
}

// --------------------------- generic LN row ---------------------------------
__device__ void ln_row(const float* X, const float* g, const float* b,
                       float* Y, ushort_t* Yh, ushort_t* Yl, int row, float* red) {
    int t = threadIdx.x;
    size_t base = (size_t)row * DM;
    __syncthreads();
    float v0 = X[base + t], v1 = X[base + t + 256];
    red[t] = v0 + v1;
    __syncthreads();
    for (int o = 128; o > 0; o >>= 1) { if (t < o) red[t] += red[t + o]; __syncthreads(); }
    float mu = red[0] * (1.0f / 512.0f);
    __syncthreads();
    float d0 = v0 - mu, d1 = v1 - mu;
    red[t] = d0 * d0 + d1 * d1;
    __syncthreads();
    for (int o = 128; o > 0; o >>= 1) { if (t < o) red[t] += red[t + o]; __syncthreads(); }
    float inv = rsqrtf(red[0] * (1.0f / 512.0f) + 1e-5f);
    float y0 = d0 * inv * g[t] + b[t];
    float y1 = d1 * inv * g[t + 256] + b[t + 256];
    Y[base + t] = y0; Y[base + t + 256] = y1;
    ushort_t h, l;
    split_bf16(y0, h, l); Yh[base + t] = h;       Yl[base + t] = l;
    split_bf16(y1, h, l); Yh[base + t + 256] = h; Yl[base + t + 256] = l;
}

// --------------------------- weight convert tile ----------------------------
__device__ void conv_tile(int job, const MegaP& p, char* SMc) {
    float* Ts = (float*)SMc;   // [64][65]
    int t = threadIdx.x;
    __syncthreads();
    const float* srcs[8] = {p.Wq0, p.Wk0, p.Wv0, p.Wo0, p.W10, p.W20, p.Wk1, p.Wv1};
    const int counts[8]  = {64, 64, 64, 64, 256, 256, 64, 64};
    const int Kds[8]     = {512, 512, 512, 512, 512, 2048, 512, 512};
    const int Nds[8]     = {512, 512, 512, 512, 2048, 512, 512, 512};
    const size_t offs[8] = {0, 262144, 524288, 786432, 1048576, 2097152, 3145728, 3407872};
    int mat = 0, tile = job;
    while (tile >= counts[mat]) { tile -= counts[mat]; ++mat; }
    const float* src = srcs[mat];
    int Kd = Kds[mat], Nd = Nds[mat];
    size_t off = offs[mat];
    int tk = tile / (Nd >> 6), tn = tile - tk * (Nd >> 6);
    int k0 = tk << 6, n0 = tn << 6;

    int rr = t >> 4, cc = (t & 15) << 2;
#pragma unroll
    for (int i = 0; i < 4; ++i) {
        const float4 v = *(const float4*)&src[(size_t)(k0 + rr + (i << 4)) * Nd + n0 + cc];
        Ts[(cc + 0) * 65 + rr + (i << 4)] = v.x;
        Ts[(cc + 1) * 65 + rr + (i << 4)] = v.y;
        Ts[(cc + 2) * 65 + rr + (i << 4)] = v.z;
        Ts[(cc + 3) * 65 + rr + (i << 4)] = v.w;
    }
    __syncthreads();
    int nr = t >> 2, kc = (t & 3) << 4;
    u16x8 h0, h1, l0, l1;
#pragma unroll
    for (int j = 0; j < 8; ++j) {
        ushort_t h, l;
        split_bf16(Ts[nr * 65 + kc + j], h, l);     h0[j] = h; l0[j] = l;
        split_bf16(Ts[nr * 65 + kc + 8 + j], h, l); h1[j] = h; l1[j] = l;
    }
    size_t di = off + (size_t)(n0 + nr) * Kd + k0 + kc;
    *(u16x8*)&p.WTh[di] = h0; *(u16x8*)&p.WTh[di + 8] = h1;
    *(u16x8*)&p.WTl[di] = l0; *(u16x8*)&p.WTl[di + 8] = l1;
}

// --------------------------- MFMA GEMM tile ---------------------------------
// mode 0: Out = acc+bias | 1: gelu->Oh/Ol bf16 pair | 2: HY += acc+bias
__device__ void mm_dev(const ushort_t* Ah, const ushort_t* Al,
                       const ushort_t* Wh, const ushort_t* Wl, const float* bias,
                       float* Out, float* HY, ushort_t* Oh, ushort_t* Ol,
                       int K, int N, int mode, int nb, int m0, char* SMc) {
    ushort_t* Ash = (ushort_t*)SMc;          // [64][72]
    ushort_t* Asl = Ash + 64 * 72;
    ushort_t* Wsh = Asl + 64 * 72;
    ushort_t* Wsl = Wsh + 64 * 72;
    const int t = threadIdx.x;
    const int wave = t >> 6, lane = t & 63;
    const int l16 = lane & 15, quad = lane >> 4;
    const int sr = t >> 2, sc = (t & 3) << 4;
    int am = m0 + sr; if (am >= T_SEQ) am = T_SEQ - 1;
    const ushort_t* agh = Ah + (size_t)am * K + sc;
    const ushort_t* agl = Al + (size_t)am * K + sc;
    const ushort_t* wgh = Wh + (size_t)(nb + sr) * K + sc;
    const ushort_t* wgl = Wl + (size_t)(nb + sr) * K + sc;

    f32x4 acc[4] = {{0.f,0.f,0.f,0.f},{0.f,0.f,0.f,0.f},
                    {0.f,0.f,0.f,0.f},{0.f,0.f,0.f,0.f}};

    for (int kc = 0; kc < K; kc += 64) {
        __syncthreads();
        *(u16x8*)&Ash[sr * 72 + sc]     = *(const u16x8*)&agh[kc];
        *(u16x8*)&Ash[sr * 72 + sc + 8] = *(const u16x8*)&agh[kc + 8];
        *(u16x8*)&Asl[sr * 72 + sc]     = *(const u16x8*)&agl[kc];
        *(u16x8*)&Asl[sr * 72 + sc + 8] = *(const u16x8*)&agl[kc + 8];
        *(u16x8*)&Wsh[sr * 72 + sc]     = *(const u16x8*)&wgh[kc];
        *(u16x8*)&Wsh[sr * 72 + sc + 8] = *(const u16x8*)&wgh[kc + 8];
        *(u16x8*)&Wsl[sr * 72 + sc]     = *(const u16x8*)&wgl[kc];
        *(u16x8*)&Wsl[sr * 72 + sc + 8] = *(const u16x8*)&wgl[kc + 8];
        __syncthreads();
#pragma unroll
        for (int ks = 0; ks < 64; ks += 32) {
            bf16x8 bh = *(const bf16x8*)&Wsh[(wave * 16 + l16) * 72 + ks + quad * 8];
            bf16x8 bl = *(const bf16x8*)&Wsl[(wave * 16 + l16) * 72 + ks + quad * 8];
#pragma unroll
            for (int mi = 0; mi < 4; ++mi) {
                bf16x8 avh = *(const bf16x8*)&Ash[(mi * 16 + l16) * 72 + ks + quad * 8];
                bf16x8 avl = *(const bf16x8*)&Asl[(mi * 16 + l16) * 72 + ks + quad * 8];
                acc[mi] = __builtin_amdgcn_mfma_f32_16x16x32_bf16(avh, bh, acc[mi], 0, 0, 0);
                acc[mi] = __builtin_amdgcn_mfma_f32_16x16x32_bf16(avh, bl, acc[mi], 0, 0, 0);
                acc[mi] = __builtin_amdgcn_mfma_f32_16x16x32_bf16(avl, bh, acc[mi], 0, 0, 0);
            }
        }
    }

    const int n = nb + wave * 16 + l16;
    const float bv = bias[n];
#pragma unroll
    for (int mi = 0; mi < 4; ++mi) {
#pragma unroll
        for (int r = 0; r < 4; ++r) {
            int m = m0 + mi * 16 + quad * 4 + r;
            if (m >= T_SEQ) continue;
            float v = acc[mi][r] + bv;
            size_t idx = (size_t)m * N + n;
            if (mode == 0) {
                Out[idx] = v;
            } else if (mode == 2) {
                HY[idx] += v;
            } else {
                v = 0.5f * v * (1.0f + erff(v * 0.7071067811865476f));
                ushort_t h, l;
                split_bf16(v, h, l);
                Oh[idx] = h; Ol[idx] = l;
            }
        }
    }
}

// --------------------------- q-tiled L1 attention ---------------------------
#define AJT 256
__device__ void attn_dev(int q0, int hb, const MegaP& p, char* SMc) {
    float* Ks   = (float*)SMc;               // [256][76]
    float* S    = (float*)(SMc + 77824);     // [16][500]
    float* Qs   = (float*)(SMc + 109824);    // [16][68]
    float* invq = (float*)(SMc + 114176);    // [16]

    const float* Q  = p.Qb;
    const float* Km = p.Kb;
    const float* V  = p.Vb;
    const int t  = threadIdx.x;
    const int qg = t >> 6;
    const int jl = t & 63;

    {
        int r = t >> 4, c4 = t & 15;
        *(float4*)&Qs[r * 68 + c4 * 4] = *(const float4*)&Q[(size_t)(q0 + r) * DM + hb + c4 * 4];
    }

    for (int itr = 0; itr < 2; ++itr) {
        int jb = itr * AJT;
        __syncthreads();
        for (int e = t; e < AJT * 16; e += 256) {
            int r = e >> 4, c4 = e & 15;
            int j = jb + r;
            float4 kv = (j < T_SEQ) ? *(const float4*)&Km[(size_t)j * DM + hb + c4 * 4]
                                    : make_float4(0.f, 0.f, 0.f, 0.f);
            *(float4*)&Ks[r * 76 + c4 * 4] = kv;
        }
        __syncthreads();

        float sacc[4][4];
#pragma unroll
        for (int a = 0; a < 4; ++a)
#pragma unroll
            for (int b = 0; b < 4; ++b) sacc[a][b] = 0.0f;

#pragma unroll 4
        for (int c4 = 0; c4 < 16; ++c4) {
            float4 qv0 = *(float4*)&Qs[(qg * 4 + 0) * 68 + c4 * 4];
            float4 qv1 = *(float4*)&Qs[(qg * 4 + 1) * 68 + c4 * 4];
            float4 qv2 = *(float4*)&Qs[(qg * 4 + 2) * 68 + c4 * 4];
            float4 qv3 = *(float4*)&Qs[(qg * 4 + 3) * 68 + c4 * 4];
            float4 kv0 = *(float4*)&Ks[(jl * 4 + 0) * 76 + c4 * 4];
            float4 kv1 = *(float4*)&Ks[(jl * 4 + 1) * 76 + c4 * 4];
            float4 kv2 = *(float4*)&Ks[(jl * 4 + 2) * 76 + c4 * 4];
            float4 kv3 = *(float4*)&Ks[(jl * 4 + 3) * 76 + c4 * 4];
#define DOT4(a, b) (a.x * b.x + a.y * b.y + a.z * b.z + a.w * b.w)
            sacc[0][0] += DOT4(qv0, kv0); sacc[0][1] += DOT4(qv0, kv1);
            sacc[0][2] += DOT4(qv0, kv2); sacc[0][3] += DOT4(qv0, kv3);
            sacc[1][0] += DOT4(qv1, kv0); sacc[1][1] += DOT4(qv1, kv1);
            sacc[1][2] += DOT4(qv1, kv2); sacc[1][3] += DOT4(qv1, kv3);
            sacc[2][0] += DOT4(qv2, kv0); sacc[2][1] += DOT4(qv2, kv1);
            sacc[2][2] += DOT4(qv2, kv2); sacc[2][3] += DOT4(qv2, kv3);
            sacc[3][0] += DOT4(qv3, kv0); sacc[3][1] += DOT4(qv3, kv1);
            sacc[3][2] += DOT4(qv3, kv2); sacc[3][3] += DOT4(qv3, kv3);
#undef DOT4
        }
        if (jb + jl * 4 < T_SEQ) {
#pragma unroll
            for (int qq = 0; qq < 4; ++qq)
                *(float4*)&S[(qg * 4 + qq) * 500 + jb + jl * 4] =
                    make_float4(sacc[qq][0] * 0.125f, sacc[qq][1] * 0.125f,
                                sacc[qq][2] * 0.125f, sacc[qq][3] * 0.125f);
        }
    }
    __syncthreads();

    {
        int q = t >> 4, jt = t & 15;
        float4* Sr = (float4*)&S[q * 500];
        float mx = -1e30f;
        for (int i = jt; i < 124; i += 16) {
            float4 v = Sr[i];
            mx = fmaxf(mx, fmaxf(fmaxf(v.x, v.y), fmaxf(v.z, v.w)));
        }
#pragma unroll
        for (int m = 1; m <= 8; m <<= 1) mx = fmaxf(mx, __shfl_xor(mx, m, 64));
        float sum = 0.0f;
        for (int i = jt; i < 124; i += 16) {
            float4 v = Sr[i];
            v.x = expf(v.x - mx); v.y = expf(v.y - mx);
            v.z = expf(v.z - mx); v.w = expf(v.w - mx);
            Sr[i] = v;
            sum += v.x + v.y + v.z + v.w;
        }
#pragma unroll
        for (int m = 1; m <= 8; m <<= 1) sum += __shfl_xor(sum, m, 64);
        if (jt == 0) invq[q] = 1.0f / sum;
    }

    float4 oacc[16];
#pragma unroll
    for (int q = 0; q < 16; ++q) oacc[q] = make_float4(0.f, 0.f, 0.f, 0.f);
    const int c4v = jl & 15, jj = jl >> 4;

    for (int ph = 0; ph < 2; ++ph) {
        int jb = ph * 248;
        __syncthreads();
        for (int e = t; e < 248 * 16; e += 256) {
            int r = e >> 4, cc = e & 15;
            *(float4*)&Ks[r * 76 + cc * 4] = *(const float4*)&V[(size_t)(jb + r) * DM + hb + cc * 4];
        }
        __syncthreads();
        for (int quad = qg; quad < 62; quad += 4) {
            int jloc = quad * 4 + jj;
            float4 v = *(float4*)&Ks[jloc * 76 + c4v * 4];
            int jg2 = jb + jloc;
#pragma unroll
            for (int q = 0; q < 16; ++q) {
                float pv = S[q * 500 + jg2];
                oacc[q].x += pv * v.x; oacc[q].y += pv * v.y;
                oacc[q].z += pv * v.z; oacc[q].w += pv * v.w;
            }
        }
    }

    __syncthreads();
    {
        int pid = qg * 4 + jj;
        float4* P4 = (float4*)Ks;
#pragma unroll
        for (int q = 0; q < 16; ++q)
            P4[(pid * 16 + q) * 16 + c4v] = oacc[q];
    }
    __syncthreads();
    {
        int q = t >> 4, cc = t & 15;
        float4* P4 = (float4*)Ks;
        float4 s = make_float4(0.f, 0.f, 0.f, 0.f);
#pragma unroll
        for (int pp = 0; pp < 16; ++pp) {
            float4 v = P4[(pp * 16 + q) * 16 + cc];
            s.x += v.x; s.y += v.y; s.z += v.z; s.w += v.w;
        }
        float iv = invq[q];
        s.x *= iv; s.y *= iv; s.z *= iv; s.w *= iv;
        size_t idx = (size_t)(q0 + q) * DM + hb + cc * 4;
        ushort_t h, l;
        ushort4 vh, vl;
        split_bf16(s.x, h, l); vh.x = h; vl.x = l;
        split_bf16(s.y, h, l); vh.y = h; vl.y = l;
        split_bf16(s.z, h, l); vh.z = h; vl.z = l;
        split_bf16(s.w, h, l); vh.w = h; vl.w = l;
        *(ushort4*)&p.Obh[idx] = vh;
        *(ushort4*)&p.Obl[idx] = vl;
    }
}

// --------------------------- L2 attention (row 495) -------------------------
__device__ void attn2_dev(int h, const MegaP& p, char* SMc) {
    float* xn   = (float*)SMc;
    float* qrow = (float*)(SMc + 2048);
    float* s    = (float*)(SMc + 2304);
    float* redw = (float*)(SMc + 4288);
    float* pacc = (float*)(SMc + 4320);
    const float* XNrow = p.XN + (size_t)(T_SEQ - 1) * DM;
    const float* Km = p.Kb;
    const float* V  = p.Vb;
    int t = threadIdx.x, hb = h * HD;

    if (t < 128) *(float4*)&xn[t * 4] = *(const float4*)&XNrow[t * 4];
    __syncthreads();

    {
        int c = t & 63, pq = t >> 6;
        float a = 0.0f;
        for (int k = pq * 128; k < pq * 128 + 128; ++k)
            a += xn[k] * p.Wq1[(size_t)k * DM + hb + c];
        pacc[pq * 68 + c] = a;
        __syncthreads();
        if (t < HD) qrow[t] = pacc[0 * 68 + t] + pacc[1 * 68 + t] + pacc[2 * 68 + t]
                            + pacc[3 * 68 + t] + p.ebq[DM + hb + t];
        __syncthreads();
    }

    float lmax = -1e30f;
    for (int j = t; j < T_SEQ; j += 256) {
        const float4* kr = (const float4*)(Km + (size_t)j * DM + hb);
        float4 a = make_float4(0.f, 0.f, 0.f, 0.f);
#pragma unroll
        for (int c4 = 0; c4 < 16; ++c4) {
            const float4 k4 = kr[c4];
            const float4 q4 = *(const float4*)&qrow[c4 * 4];
            a.x += q4.x * k4.x; a.y += q4.y * k4.y;
            a.z += q4.z * k4.z; a.w += q4.w * k4.w;
        }
        float d = (a.x + a.y + a.z + a.w) * 0.125f;
        s[j] = d;
        lmax = fmaxf(lmax, d);
    }
#pragma unroll
    for (int o = 32; o > 0; o >>= 1) lmax = fmaxf(lmax, __shfl_xor(lmax, o, 64));
    if ((t & 63) == 0) redw[t >> 6] = lmax;
    __syncthreads();
    float mx = fmaxf(fmaxf(redw[0], redw[1]), fmaxf(redw[2], redw[3]));

    float lsum = 0.0f;
    for (int j = t; j < T_SEQ; j += 256) {
        float e = expf(s[j] - mx);
        s[j] = e;
        lsum += e;
    }
#pragma unroll
    for (int o = 32; o > 0; o >>= 1) lsum += __shfl_xor(lsum, o, 64);
    if ((t & 63) == 0) redw[4 + (t >> 6)] = lsum;
    __syncthreads();
    float inv = 1.0f / (redw[4] + redw[5] + redw[6] + redw[7]);

    int cg4 = t & 15, jg = t >> 4;
    int c = cg4 * 4;
    float4 acc = make_float4(0.f, 0.f, 0.f, 0.f);
    for (int j = jg; j < T_SEQ; j += 16) {
        float pv = s[j];
        const float4 v4 = *(const float4*)&V[(size_t)j * DM + hb + c];
        acc.x += pv * v4.x; acc.y += pv * v4.y; acc.z += pv * v4.z; acc.w += pv * v4.w;
    }
    __syncthreads();
    *(float4*)&pacc[jg * 68 + c] = acc;
    __syncthreads();
    if (t < HD) {
        float r = 0.0f;
#pragma unroll
        for (int g = 0; g < 16; ++g) r += pacc[g * 68 + t];
        p.O2[hb + t] = r * inv;
    }
}

// --------------------------- split-K GEMV -----------------------------------
__device__ void gemv_dev(const float* x, const float* W, float* P,
                         int K, int N, int bxx, int byy, char* SMc) {
    float* xs = (float*)SMc;
    float4* pac = (float4*)(SMc + 256);
    int t = threadIdx.x;
    __syncthreads();
    int c4 = bxx * 64 + (t & 63);
    int pq = t >> 6;
    int kb = byy * 64;
    if (t < 64) xs[t] = x[kb + t];
    __syncthreads();
    const float4* W4 = (const float4*)W;
    int n4 = N >> 2;
    float4 a = make_float4(0.f, 0.f, 0.f, 0.f);
    int k0 = pq * 16;
#pragma unroll
    for (int i = 0; i < 16; ++i) {
        float xv = xs[k0 + i];
        const float4 w = W4[(size_t)(kb + k0 + i) * n4 + c4];
        a.x += xv * w.x; a.y += xv * w.y; a.z += xv * w.z; a.w += xv * w.w;
    }
    pac[pq * 64 + (t & 63)] = a;
    __syncthreads();
    if (t < 64) {
        float4 r0 = pac[0 * 64 + t], r1 = pac[1 * 64 + t];
        float4 r2 = pac[2 * 64 + t], r3 = pac[3 * 64 + t];
        float4 r = make_float4(r0.x + r1.x + r2.x + r3.x, r0.y + r1.y + r2.y + r3.y,
                               r0.z + r1.z + r2.z + r3.z, r0.w + r1.w + r2.w + r3.w);
        *(float4*)&P[(size_t)byy * N + (size_t)(bxx * 64 + t) * 4] = r;
    }
}

__device__ void gemv_reduce_dev(const float* P, const float* bias, float* out,
                                int N, int nch, int mode, int part) {
    int idx4 = (part * 256 + threadIdx.x) * 4;
    if (idx4 >= N) return;
    const float4 b4 = *(const float4*)&bias[idx4];
    float4 s = b4;
    for (int ch = 0; ch < nch; ++ch) {
        const float4 pp = *(const float4*)&P[(size_t)ch * N + idx4];
        s.x += pp.x; s.y += pp.y; s.z += pp.z; s.w += pp.w;
    }
    if (mode == 1) {
        s.x = 0.5f * s.x * (1.0f + erff(s.x * 0.7071067811865476f));
        s.y = 0.5f * s.y * (1.0f + erff(s.y * 0.7071067811865476f));
        s.z = 0.5f * s.z * (1.0f + erff(s.z * 0.7071067811865476f));
        s.w = 0.5f * s.w * (1.0f + erff(s.w * 0.7071067811865476f));
    }
    *(float4*)&out[idx4] = s;
}

__device__ void red_ln_dev(const MegaP& p, float* red) {
    int t = threadIdx.x;
    float* Hrow = p.H + (size_t)(T_SEQ - 1) * DM;
    __syncthreads();
    float v0 = Hrow[t] + p.ebo[DM + t], v1 = Hrow[t + 256] + p.ebo[DM + t + 256];
    for (int ch = 0; ch < 8; ++ch) {
        v0 += p.Pp[ch * DM + t];
        v1 += p.Pp[ch * DM + t + 256];
    }
    Hrow[t] = v0; Hrow[t + 256] = v1;

    red[t] = v0 + v1;
    __syncthreads();
    for (int o = 128; o > 0; o >>= 1) { if (t < o) red[t] += red[t + o]; __syncthreads(); }
    float mu = red[0] * (1.0f / 512.0f);
    __syncthreads();
    float d0 = v0 - mu, d1 = v1 - mu;
    red[t] = d0 * d0 + d1 * d1;
    __syncthreads();
    for (int o = 128; o > 0; o >>= 1) { if (t < o) red[t] += red[t + o]; __syncthreads(); }
    float inv = rsqrtf(red[0] * (1.0f / 512.0f) + 1e-5f);
    p.xrow[t]       = d0 * inv * p.ln2_g[DM + t]       + p.ln2_b[DM + t];
    p.xrow[t + 256] = d1 * inv * p.ln2_g[DM + t + 256] + p.ln2_b[DM + t + 256];
}

__device__ void final_dev(const MegaP& p, float* red) {
    int t = threadIdx.x;
    float* Hrow = p.H + (size_t)(T_SEQ - 1) * DM;
    __syncthreads();
    float v0 = Hrow[t] + p.eb2[DM + t], v1 = Hrow[t + 256] + p.eb2[DM + t + 256];
    for (int ch = 0; ch < 32; ++ch) {
        v0 += p.Pp[ch * DM + t];
        v1 += p.Pp[ch * DM + t + 256];
    }
    red[t] = v0 + v1;
    __syncthreads();
    for (int o = 128; o > 0; o >>= 1) { if (t < o) red[t] += red[t + o]; __syncthreads(); }
    float mu = red[0] * (1.0f / 512.0f);
    __syncthreads();
    float d0 = v0 - mu, d1 = v1 - mu;
    red[t] = d0 * d0 + d1 * d1;
    __syncthreads();
    for (int o = 128; o > 0; o >>= 1) { if (t < o) red[t] += red[t + o]; __syncthreads(); }
    float inv = rsqrtf(red[0] * (1.0f / 512.0f) + 1e-5f);
    __syncthreads();
    float h0 = d0 * inv * p.fn_g[t] + p.fn_b[t];
    float h1 = d1 * inv * p.fn_g[t + 256] + p.fn_b[t + 256];
    red[t] = h0 * p.Wc[t] + h1 * p.Wc[t + 256];
    __syncthreads();
    for (int o = 128; o > 0; o >>= 1) { if (t < o) red[t] += red[t + o]; __syncthreads(); }
    float r = red[0] + p.bc[0];
    if (t < 64) p.out[t] = r;
}

// --------------------------- the mega kernel --------------------------------
__global__ __launch_bounds__(256)
void mega_kernel(MegaP p) {
    __shared__ __align__(16) char SM[114240];
    const int bx = blockIdx.x;

    // S0: weight convert + pos-enc/LN
    for (int job = bx; job < 896; job += NBLK) conv_tile(job, p, SM);
    for (int row = bx; row < T_SEQ; row += NBLK) ln_pe_row(row, p, (float*)(SM + 16640));
    gsync(p.bar);
    // S1: QKV projections (192 tile jobs)
    if (bx < 192) {
        int mat = bx >> 6, tile = bx & 63;
        const float* bias = (mat == 0) ? p.ebq : (mat == 1) ? p.ebk : p.ebv;
        mm_dev(p.XNh, p.XNl, p.WTh + (size_t)mat * 262144, p.WTl + (size_t)mat * 262144,
               bias, p.Qb + (size_t)mat * SEQF, nullptr, nullptr, nullptr,
               DM, DM, 0, (tile & 7) * 64, (tile >> 3) * 64, SM);
    }
    gsync(p.bar);
    // S2: L1 attention (248 jobs)
    if (bx < 248) attn_dev((bx >> 3) * 16, (bx & 7) * 64, p, SM);
    gsync(p.bar);
    // S3: Wo residual (64 jobs)
    if (bx < 64) mm_dev(p.Obh, p.Obl, p.WTh + 786432, p.WTl + 786432, p.ebo,
                        nullptr, p.H, nullptr, nullptr, DM, DM, 2,
                        (bx & 7) * 64, (bx >> 3) * 64, SM);
    gsync(p.bar);
    // S4: LN2
    for (int row = bx; row < T_SEQ; row += NBLK)
        ln_row(p.H, p.ln2_g, p.ln2_b, p.XN, p.XNh, p.XNl, row, (float*)SM);
    gsync(p.bar);
    // S5: FF1 gelu (256 jobs)
    mm_dev(p.XNh, p.XNl, p.WTh + 1048576, p.WTl + 1048576, p.eb1,
           nullptr, nullptr, p.Fbh, p.Fbl, DM, FF, 1,
           (bx & 31) * 64, (bx >> 5) * 64, SM);
    gsync(p.bar);
    // S6: FF2 residual (64 jobs)
    if (bx < 64) mm_dev(p.Fbh, p.Fbl, p.WTh + 2097152, p.WTl + 2097152, p.eb2,
                        nullptr, p.H, nullptr, nullptr, FF, DM, 2,
                        (bx & 7) * 64, (bx >> 3) * 64, SM);
    gsync(p.bar);
    // S7: L2 LN1
    for (int row = bx; row < T_SEQ; row += NBLK)
        ln_row(p.H, p.ln1_g + DM, p.ln1_b + DM, p.XN, p.XNh, p.XNl, row, (float*)SM);
    gsync(p.bar);
    // S8: L2 K/V (128 jobs)
    if (bx < 128) {
        int mat = bx >> 6, tile = bx & 63;
        mm_dev(p.XNh, p.XNl, p.WTh + 3145728 + (size_t)mat * 262144,
               p.WTl + 3145728 + (size_t)mat * 262144,
               (mat == 0) ? p.ebk + DM : p.ebv + DM,
               (mat == 0) ? p.Kb : p.Vb, nullptr, nullptr, nullptr,
               DM, DM, 0, (tile & 7) * 64, (tile >> 3) * 64, SM);
    }
    gsync(p.bar);
    // S9: L2 attention (8 jobs)
    if (bx < NH) attn2_dev(bx, p, SM);
    gsync(p.bar);
    // S10: O2 @ Wo1 partials (16 jobs)
    if (bx < 16) gemv_dev(p.O2, p.Wo1, p.Pp, DM, DM, bx & 1, bx >> 1, SM);
    gsync(p.bar);
    // S11: reduce + residual + LN
    if (bx == 0) red_ln_dev(p, (float*)SM);
    gsync(p.bar);
    // S12: xrow @ W11 partials (64 jobs)
    if (bx < 64) gemv_dev(p.xrow, p.W11, p.Pp, DM, FF, bx & 7, bx >> 3, SM);
    gsync(p.bar);
    // S13: reduce + gelu (2 jobs)
    if (bx < 2) gemv_reduce_dev(p.Pp, p.eb1 + FF, p.Fr, FF, 8, 1, bx);
    gsync(p.bar);
    // S14: Fr @ W21 partials (64 jobs)
    if (bx < 64) gemv_dev(p.Fr, p.W21, p.Pp, FF, DM, bx & 1, bx >> 1, SM);
    gsync(p.bar);
    // S15: final reduce + LN + head + broadcast
    if (bx == 0) final_dev(p, (float*)SM);
}

// -------------------------------------------------------------------- host --
extern "C" void kernel_launch(void* const* d_in, const int* in_sizes, int n_in,
                              void* d_out, int out_size, void* d_ws, size_t ws_size,
                              hipStream_t stream) {
    const float* ln1_g = (const float*)d_in[19];
    const float* ln1_b = (const float*)d_in[20];
    const float* eWq   = (const float*)d_in[21];
    const float* ebq   = (const float*)d_in[22];
    const float* eWk   = (const float*)d_in[23];
    const float* ebk   = (const float*)d_in[24];
    const float* eWv   = (const float*)d_in[25];
    const float* ebv   = (const float*)d_in[26];
    const float* eWo   = (const float*)d_in[27];
    const float* ebo   = (const float*)d_in[28];
    const float* ln2_g = (const float*)d_in[29];
    const float* ln2_b = (const float*)d_in[30];
    const float* eW1   = (const float*)d_in[31];
    const float* eb1   = (const float*)d_in[32];
    const float* eW2   = (const float*)d_in[33];
    const float* eb2   = (const float*)d_in[34];
    const float* fn_g  = (const float*)d_in[35];
    const float* fn_b  = (const float*)d_in[36];
    const float* Wc    = (const float*)d_in[37];
    const float* bc    = (const float*)d_in[38];

    const size_t S = SEQF;
    float* H    = (float*)d_ws;
    float* XN   = H + S;
    float* Qb   = XN + S;
    float* Kb   = Qb + S;
    float* Vb   = Kb + S;
    float* Pp   = Qb + 3 * S;
    float* O2   = Pp + 16384;
    float* xrow = O2 + DM;
    float* Fr   = xrow + DM;
    ushort_t* XNh = (ushort_t*)(Fr + 2048 + 1024);
    ushort_t* XNl = XNh + S;
    ushort_t* Obh = XNl + S;
    ushort_t* Obl = Obh + S;
    ushort_t* Fbh = Obl + S;
    ushort_t* Fbl = Fbh + (size_t)T_SEQ * FF;
    ushort_t* WTh = Fbl + (size_t)T_SEQ * FF;
    ushort_t* WTl = WTh + 3670016;
    unsigned* bar = (unsigned*)(WTl + 3670016 + 64);   // barrier counters

    MegaP p;
    p.Wq0 = eWq; p.Wk0 = eWk; p.Wv0 = eWv; p.Wo0 = eWo;
    p.W10 = eW1; p.W20 = eW2;
    p.Wk1 = eWk + (size_t)DM * DM;
    p.Wv1 = eWv + (size_t)DM * DM;
    p.Wq1 = eWq + (size_t)DM * DM;
    p.Wo1 = eWo + (size_t)DM * DM;
    p.W11 = eW1 + (size_t)DM * FF;
    p.W21 = eW2 + (size_t)FF * DM;
    p.ln1_g = ln1_g; p.ln1_b = ln1_b; p.ln2_g = ln2_g; p.ln2_b = ln2_b;
    p.fn_g = fn_g; p.fn_b = fn_b; p.Wc = Wc; p.bc = bc;
    p.ebq = ebq; p.ebk = ebk; p.ebv = ebv; p.ebo = ebo; p.eb1 = eb1; p.eb2 = eb2;
    p.H = H; p.XN = XN; p.Qb = Qb; p.Kb = Kb; p.Vb = Vb;
    p.Pp = Pp; p.O2 = O2; p.xrow = xrow; p.Fr = Fr;
    p.XNh = XNh; p.XNl = XNl; p.Obh = Obh; p.Obl = Obl;
    p.Fbh = Fbh; p.Fbl = Fbl; p.WTh = WTh; p.WTl = WTl;
    p.bar = bar;
    p.out = (float*)d_out;

    // zero the barrier counters (workspace is re-poisoned before every launch)
    hipMemsetAsync(bar, 0, 256, stream);
    mega_kernel<<<NBLK, 256, 0, stream>>>(p);
}